// Round 4
// baseline (645.216 us; speedup 1.0000x reference)
//
#include <hip/hip_runtime.h>

// Problem constants (fixed by reference setup_inputs)
#define BATCH 16
#define HH 64
#define WW 64
#define CC 1024
#define GG 32
#define CG 32          // channels per group
#define TH 8           // tile rows per block
#define TW 16          // tile cols per block
#define EPS 1e-3f
#define ALPHA 0.3f

typedef float v2f __attribute__((ext_vector_type(2)));

// LDS: y tile only. 128 px * 36 floats = 18432 B -> 8 blocks/CU by LDS.
#define YS_STRIDE 36
#define YS_FLOATS (TH * TW * YS_STRIDE)

// one halo row: 3 clamped+masked x loads feeding up to 3 accumulators
#define ROWLD \
    v2f x0 = *(const v2f*)(rrp + o0) * cm0; \
    v2f x1 = *(const v2f*)(rrp + o1); \
    v2f x2 = *(const v2f*)(rrp + o2) * cm2;

#define ROW3(AA, BB, CC_) { \
    ROWLD \
    AA  += x0 * k0 + x1 * k1 + x2 * k2; \
    BB  += x0 * k3 + x1 * k4 + x2 * k5; \
    CC_ += x0 * k6 + x1 * k7 + x2 * k8; \
    rrp += WW * CC; }

#define PWSTEP(J, YA, YB) { \
    const float* wj = wcp + (J) * CG; \
    float4 wA = *(const float4*)(wj); \
    float4 wB = *(const float4*)(wj + 4); \
    v2f wv0 = {wA.x, wA.y}, wv1 = {wA.z, wA.w}; \
    v2f wv2 = {wB.x, wB.y}, wv3 = {wB.z, wB.w}; \
    p0a += wv0 * (YA); p1a += wv1 * (YA); p2a += wv2 * (YA); p3a += wv3 * (YA); \
    p0b += wv0 * (YB); p1b += wv1 * (YB); p2b += wv2 * (YB); p3b += wv3 * (YB); }

#define LR(v) ((v) >= 0.f ? (v) : ALPHA * (v))

__global__ __launch_bounds__(256, 4)
void fused_dw_pw_bn_lrelu(const float* __restrict__ x,
                          const float* __restrict__ dwk,   // (3,3,1,C)
                          const float* __restrict__ pwk,   // (G,Cg,Cg)
                          const float* __restrict__ gamma,
                          const float* __restrict__ beta,
                          const float* __restrict__ mmean,
                          const float* __restrict__ mvar,
                          float* __restrict__ out) {
    __shared__ float smem[YS_FLOATS];

    const int t     = threadIdx.x;
    const int tile  = blockIdx.x;               // 0..31
    const int tw0   = (tile & 3) * TW;          // tilesW = 4
    const int th0   = (tile >> 2) * TH;
    const int g     = blockIdx.y;               // 0..31
    const int b     = blockIdx.z;               // 0..15
    const int cbase = g * CG;

    // ---------- depthwise: thread = (channel pair c2, column pcol), 8 rows ----------
    const int c2i  = t & 15;
    const int c2   = c2i * 2;
    const int pcol = t >> 4;                    // 0..15

    const float* kp = dwk + cbase + c2;
    v2f k0 = *(const v2f*)(kp + 0 * CC), k1 = *(const v2f*)(kp + 1 * CC), k2 = *(const v2f*)(kp + 2 * CC);
    v2f k3 = *(const v2f*)(kp + 3 * CC), k4 = *(const v2f*)(kp + 4 * CC), k5 = *(const v2f*)(kp + 5 * CC);
    v2f k6 = *(const v2f*)(kp + 6 * CC), k7 = *(const v2f*)(kp + 7 * CC), k8 = *(const v2f*)(kp + 8 * CC);

    // column taps: gw = tw0 + pcol - 1 + dx; clamp address, zero via mask
    const int gw0 = tw0 + pcol - 1;
    const int gw2 = gw0 + 2;
    const float cm0 = (gw0 >= 0) ? 1.f : 0.f;
    const float cm2 = (gw2 < WW) ? 1.f : 0.f;
    const int o0 = ((gw0 < 0) ? 0 : gw0) * CC;
    const int o1 = (gw0 + 1) * CC;
    const int o2 = ((gw2 >= WW) ? (WW - 1) : gw2) * CC;

    // row pointer starts at gh = th0 (halo row R=1)
    const float* rrp = x + ((size_t)(b * HH + th0) * WW) * CC + cbase + c2;

    v2f a0 = {0.f, 0.f};
    v2f a1 = a0, a2 = a0, a3 = a0, a4 = a0, a5 = a0, a6 = a0, a7 = a0;

    if (th0 > 0) {                              // halo row 0 (gh = th0-1): a0/dy0
        const float* q = rrp - WW * CC;
        v2f x0 = *(const v2f*)(q + o0) * cm0;
        v2f x1 = *(const v2f*)(q + o1);
        v2f x2 = *(const v2f*)(q + o2) * cm2;
        a0 += x0 * k0 + x1 * k1 + x2 * k2;
    }
    {                                           // halo row 1 (gh = th0): a1/dy0, a0/dy1
        ROWLD
        a1 += x0 * k0 + x1 * k1 + x2 * k2;
        a0 += x0 * k3 + x1 * k4 + x2 * k5;
        rrp += WW * CC;
    }
    ROW3(a2, a1, a0)                            // halo rows 2..7
    ROW3(a3, a2, a1)
    ROW3(a4, a3, a2)
    ROW3(a5, a4, a3)
    ROW3(a6, a5, a4)
    ROW3(a7, a6, a5)
    {                                           // halo row 8 (gh = th0+7): a7/dy1, a6/dy2
        ROWLD
        a7 += x0 * k3 + x1 * k4 + x2 * k5;
        a6 += x0 * k6 + x1 * k7 + x2 * k8;
        rrp += WW * CC;
    }
    if (th0 < HH - TH) {                        // halo row 9 (gh = th0+8): a7/dy2
        ROWLD
        a7 += x0 * k6 + x1 * k7 + x2 * k8;
    }

    // y tile to LDS: pixel p = row*TW + pcol, channels c2..c2+1
    {
        float* ys = smem + pcol * YS_STRIDE + c2;
        *(v2f*)(ys + 0 * TW * YS_STRIDE) = a0;
        *(v2f*)(ys + 1 * TW * YS_STRIDE) = a1;
        *(v2f*)(ys + 2 * TW * YS_STRIDE) = a2;
        *(v2f*)(ys + 3 * TW * YS_STRIDE) = a3;
        *(v2f*)(ys + 4 * TW * YS_STRIDE) = a4;
        *(v2f*)(ys + 5 * TW * YS_STRIDE) = a5;
        *(v2f*)(ys + 6 * TW * YS_STRIDE) = a6;
        *(v2f*)(ys + 7 * TW * YS_STRIDE) = a7;
    }

    __syncthreads();    // the only barrier

    // ---------- pointwise: thread = (8 out-channels d8, pixels px0 and px0+64) ----------
    const int d8  = (t & 3) * 8;
    const int px0 = t >> 2;                     // 0..63
    const float* wg = pwk + (size_t)g * CG * CG + d8;

    v2f p0a = {0.f, 0.f}, p1a = p0a, p2a = p0a, p3a = p0a;
    v2f p0b = p0a, p1b = p0a, p2b = p0a, p3b = p0a;

    #pragma unroll
    for (int cq = 0; cq < 8; ++cq) {
        const float* wcp = wg + cq * 4 * CG;
        float4 ya = *(const float4*)(smem + px0 * YS_STRIDE + cq * 4);
        float4 yb = *(const float4*)(smem + px0 * YS_STRIDE + 64 * YS_STRIDE + cq * 4);
        PWSTEP(0, ya.x, yb.x)
        PWSTEP(1, ya.y, yb.y)
        PWSTEP(2, ya.z, yb.z)
        PWSTEP(3, ya.w, yb.w)
    }

    // ---------- BN constants for d8..d8+7 ----------
    float4 gA = *(const float4*)(gamma + cbase + d8), gB = *(const float4*)(gamma + cbase + d8 + 4);
    float4 vA = *(const float4*)(mvar  + cbase + d8), vB = *(const float4*)(mvar  + cbase + d8 + 4);
    float4 bA = *(const float4*)(beta  + cbase + d8), bB = *(const float4*)(beta  + cbase + d8 + 4);
    float4 mA = *(const float4*)(mmean + cbase + d8), mB = *(const float4*)(mmean + cbase + d8 + 4);
    float s0 = gA.x * rsqrtf(vA.x + EPS), s1 = gA.y * rsqrtf(vA.y + EPS);
    float s2 = gA.z * rsqrtf(vA.z + EPS), s3 = gA.w * rsqrtf(vA.w + EPS);
    float s4 = gB.x * rsqrtf(vB.x + EPS), s5 = gB.y * rsqrtf(vB.y + EPS);
    float s6 = gB.z * rsqrtf(vB.z + EPS), s7 = gB.w * rsqrtf(vB.w + EPS);
    float c0 = bA.x - mA.x * s0, c1 = bA.y - mA.y * s1;
    float c2b = bA.z - mA.z * s2, c3 = bA.w - mA.w * s3;
    float c4 = bB.x - mB.x * s4, c5 = bB.y - mB.y * s5;
    float c6 = bB.z - mB.z * s6, c7 = bB.w - mB.w * s7;

    // ---------- BN + LeakyReLU + stores (2 pixels x 8 channels) ----------
    const int pr = px0 >> 4, pc = px0 & 15;
    float* op = out + ((size_t)(b * HH + th0 + pr) * WW + (tw0 + pc)) * CC + cbase + d8;
    {
        float z0 = LR(p0a.x * s0 + c0),  z1 = LR(p0a.y * s1 + c1);
        float z2 = LR(p1a.x * s2 + c2b), z3 = LR(p1a.y * s3 + c3);
        float z4 = LR(p2a.x * s4 + c4),  z5 = LR(p2a.y * s5 + c5);
        float z6 = LR(p3a.x * s6 + c6),  z7 = LR(p3a.y * s7 + c7);
        *(float4*)(op)     = make_float4(z0, z1, z2, z3);
        *(float4*)(op + 4) = make_float4(z4, z5, z6, z7);
    }
    {   // second pixel: px0+64 -> row pr+4, same column
        float* op2 = op + (size_t)4 * WW * CC;
        float z0 = LR(p0b.x * s0 + c0),  z1 = LR(p0b.y * s1 + c1);
        float z2 = LR(p1b.x * s2 + c2b), z3 = LR(p1b.y * s3 + c3);
        float z4 = LR(p2b.x * s4 + c4),  z5 = LR(p2b.y * s5 + c5);
        float z6 = LR(p3b.x * s6 + c6),  z7 = LR(p3b.y * s7 + c7);
        *(float4*)(op2)     = make_float4(z0, z1, z2, z3);
        *(float4*)(op2 + 4) = make_float4(z4, z5, z6, z7);
    }
}

extern "C" void kernel_launch(void* const* d_in, const int* in_sizes, int n_in,
                              void* d_out, int out_size, void* d_ws, size_t ws_size,
                              hipStream_t stream) {
    const float* x     = (const float*)d_in[0];
    const float* dwk   = (const float*)d_in[1];
    const float* pwk   = (const float*)d_in[2];
    const float* gamma = (const float*)d_in[3];
    const float* beta  = (const float*)d_in[4];
    const float* mmean = (const float*)d_in[5];
    const float* mvar  = (const float*)d_in[6];
    float* out = (float*)d_out;

    dim3 grid((HH / TH) * (WW / TW), GG, BATCH);  // (32, 32, 16)
    dim3 block(256);
    hipLaunchKernelGGL(fused_dw_pw_bn_lrelu, grid, block, 0, stream,
                       x, dwk, pwk, gamma, beta, mmean, mvar, out);
}